// Round 2
// baseline (699.135 us; speedup 1.0000x reference)
//
#include <hip/hip_runtime.h>
#include <math.h>

#define BB 2
#define NCAM 6
#define CC 256
#define HH 116
#define WW 200
#define QQ 900
#define DD 256
#define NHD 8
#define HD 32
#define HWSZ (HH*WW)
#define QT 8

__device__ __forceinline__ float sigmoidf_(float x){ return 1.0f/(1.0f+expf(-x)); }

// ---------------- ref = sigmoid(q @ ref_w.T + ref_b)  [Q,3] ----------------
__global__ void ref_kernel(const float* __restrict__ qe, const float* __restrict__ ref_w,
                           const float* __restrict__ ref_b, float* __restrict__ ref) {
    int idx = blockIdx.x*256 + threadIdx.x;
    if (idx >= QQ*3) return;
    int q = idx/3, j = idx%3;
    float acc = ref_b[j];
    const float* qr = qe + q*DD;
    const float* wr = ref_w + j*DD;
    for (int k=0;k<DD;k++) acc += qr[k]*wr[k];
    ref[idx] = sigmoidf_(acc);
}

// ---------------- project ref points to each camera ----------------
// Stores bilinear params ALWAYS, plus separate flags:
//   maskz[bn*QQ+q]  = (z > 1e-5)
//   inimg[bn*QQ+q]  = (max(|pnx|,|pny|) < 1)
// valid(b,q,n) is assembled in sample_kernel with the reference's reshape quirk.
__global__ void proj_kernel(const float* __restrict__ l2i, const float* __restrict__ ref,
        float* __restrict__ wxa, float* __restrict__ wya,
        int* __restrict__ x0a, int* __restrict__ y0a,
        int* __restrict__ maskz, int* __restrict__ inimg) {
    int idx = blockIdx.x*256+threadIdx.x;
    if (idx >= BB*NCAM*QQ) return;
    int q = idx % QQ;
    int bn = idx / QQ;   // b*NCAM+n
    float h0 = ref[q*3+0], h1 = ref[q*3+1], h2 = ref[q*3+2];
    const float* m = l2i + bn*16;
    float px = m[0]*h0+m[1]*h1+m[2]*h2+m[3];
    float py = m[4]*h0+m[5]*h1+m[6]*h2+m[7];
    float pz = m[8]*h0+m[9]*h1+m[10]*h2+m[11];
    float denom = fabsf(pz)+1e-5f;
    float sx = px/denom, sy = py/denom;
    float pnx = sx/(float)(WW-1)*2.0f-1.0f;
    float pny = sy/(float)(HH-1)*2.0f-1.0f;
    maskz[idx] = (pz > 1e-5f) ? 1 : 0;
    inimg[idx] = (fmaxf(fabsf(pnx),fabsf(pny)) < 1.0f) ? 1 : 0;
    // bilinear params (align_corners=False): always stored
    float ix = (pnx+1.0f)*(WW*0.5f)-0.5f;
    float iy = (pny+1.0f)*(HH*0.5f)-0.5f;
    float x0f = floorf(ix), y0f = floorf(iy);
    wxa[idx] = ix-x0f; wya[idx] = iy-y0f;
    // float->int saturates on AMD; out-of-range corners rejected by unsigned checks later
    x0a[idx] = (int)x0f; y0a[idx] = (int)y0f;
}

// ---------------- bilinear gather + masked mean over cams + add q ----------------
__global__ __launch_bounds__(256) void sample_kernel(const float* __restrict__ feats,
        const float* __restrict__ qe, const float* __restrict__ wxa, const float* __restrict__ wya,
        const int* __restrict__ x0a, const int* __restrict__ y0a,
        const int* __restrict__ maskz, const int* __restrict__ inimg,
        float* __restrict__ xout) {
    int bq = blockIdx.x;
    int b = bq / QQ, q = bq % QQ;
    int c = threadIdx.x;
    float sum = 0.0f;
    int cnt = 0;
    for (int n = 0; n < NCAM; n++) {
        int s = (b*NCAM+n)*QQ + q;          // matched (b,n,q) index
        // Reference quirk: in-image flag comes from the (N,Q)->(Q,N) RESHAPE,
        // i.e. flat element f = q*NCAM+n of the per-batch pn block.
        int sq = b*(NCAM*QQ) + q*NCAM + n;  // scrambled index
        int v = maskz[s] & inimg[sq];
        if (!v) continue;
        cnt++;
        float wx = wxa[s], wy = wya[s];
        int x0 = x0a[s], y0 = y0a[s];
        int x1 = x0+1, y1 = y0+1;
        const float* fb = feats + ((size_t)(b*NCAM+n)*CC + c)*HWSZ;
        float w00 = (1.f-wx)*(1.f-wy), w10 = wx*(1.f-wy), w01 = (1.f-wx)*wy, w11 = wx*wy;
        bool xin0 = ((unsigned)x0 < (unsigned)WW);
        bool xin1 = ((unsigned)x1 < (unsigned)WW);
        if ((unsigned)y0 < (unsigned)HH) {
            const float* row = fb + y0*WW;
            if (xin0) sum += w00*row[x0];
            if (xin1) sum += w10*row[x1];
        }
        if ((unsigned)y1 < (unsigned)HH) {
            const float* row = fb + y1*WW;
            if (xin0) sum += w01*row[x0];
            if (xin1) sum += w11*row[x1];
        }
    }
    float tgt = sum / (float)(cnt > 0 ? cnt : 1);
    xout[(size_t)bq*DD + c] = qe[q*DD+c] + tgt;
}

// ---------------- tiled SGEMM: C[M,N] = A[M,K] @ Wt[N,K]^T + bias[N] ----------------
#define TILE 64
#define BKK 16
__global__ __launch_bounds__(256) void sgemm_nt(const float* __restrict__ A,
        const float* __restrict__ Bw, const float* __restrict__ bias,
        float* __restrict__ Cm, int M, int N, int K) {
    __shared__ float As[BKK][TILE];
    __shared__ float Bs[BKK][TILE];
    int tid = threadIdx.x;
    int m0 = blockIdx.y * TILE, n0 = blockIdx.x * TILE;
    float acc[4][4] = {};
    int tx = tid & 15, ty = tid >> 4;
    for (int k0 = 0; k0 < K; k0 += BKK) {
        #pragma unroll
        for (int i = 0; i < 4; i++) {
            int idx = tid + i * 256;
            int m = idx >> 4;
            int k = idx & 15;
            int gm = m0 + m;
            As[k][m] = (gm < M) ? A[(size_t)gm * K + k0 + k] : 0.0f;
            int gn = n0 + m;
            Bs[k][m] = (gn < N) ? Bw[(size_t)gn * K + k0 + k] : 0.0f;
        }
        __syncthreads();
        #pragma unroll
        for (int k = 0; k < BKK; k++) {
            float a[4], bb[4];
            #pragma unroll
            for (int i = 0; i < 4; i++) a[i] = As[k][ty*4+i];
            #pragma unroll
            for (int j = 0; j < 4; j++) bb[j] = Bs[k][tx*4+j];
            #pragma unroll
            for (int i = 0; i < 4; i++)
                #pragma unroll
                for (int j = 0; j < 4; j++)
                    acc[i][j] += a[i] * bb[j];
        }
        __syncthreads();
    }
    for (int i = 0; i < 4; i++) {
        int gm = m0 + ty*4 + i;
        if (gm >= M) continue;
        for (int j = 0; j < 4; j++) {
            int gn = n0 + tx*4 + j;
            if (gn < N) Cm[(size_t)gm * N + gn] = acc[i][j] + bias[gn];
        }
    }
}

// ---------------- attention: per (b, h, 8-query tile) ----------------
__global__ __launch_bounds__(256) void attn_kernel(const float* __restrict__ qkv,
                                                   float* __restrict__ attn_out) {
    __shared__ float s_sc[QT][QQ];      // exp(scores)
    __shared__ float s_q[QT][HD];
    __shared__ float s_inv[QT];
    __shared__ float s_o[8][QT][HD];
    const int nqb = (QQ + QT - 1)/QT;   // 113
    int blk = blockIdx.x;
    int qb = blk % nqb;
    int h = (blk / nqb) % NHD;
    int b = blk / (nqb*NHD);
    int q0 = qb*QT;
    int t = threadIdx.x;
    {
        int qi = t >> 5, d = t & 31;
        float v = 0.f;
        int gq = q0 + qi;
        if (gq < QQ) v = qkv[((size_t)(b*QQ+gq))*768 + h*HD + d];
        s_q[qi][d] = v;
    }
    __syncthreads();
    const float scale = 0.17677669529663689f; // 1/sqrt(32)
    for (int k = t; k < QQ; k += 256) {
        const float* kv = qkv + ((size_t)(b*QQ+k))*768 + 256 + h*HD;
        float kr[HD];
        #pragma unroll
        for (int d=0; d<HD; d+=4) {
            float4 f = *(const float4*)(kv+d);
            kr[d]=f.x; kr[d+1]=f.y; kr[d+2]=f.z; kr[d+3]=f.w;
        }
        #pragma unroll
        for (int qi=0; qi<QT; qi++) {
            float acc = 0.f;
            #pragma unroll
            for (int d=0; d<HD; d++) acc += s_q[qi][d]*kr[d];
            s_sc[qi][k] = acc * scale;
        }
    }
    __syncthreads();
    {   // softmax per row; 32 lanes per row
        int qi = t >> 5, lane = t & 31;
        float m = -1e30f;
        for (int k=lane; k<QQ; k+=32) m = fmaxf(m, s_sc[qi][k]);
        for (int off=16; off>0; off>>=1) m = fmaxf(m, __shfl_down(m, off, 32));
        m = __shfl(m, 0, 32);
        float ssum = 0.f;
        for (int k=lane; k<QQ; k+=32) { float e = expf(s_sc[qi][k]-m); s_sc[qi][k] = e; ssum += e; }
        for (int off=16; off>0; off>>=1) ssum += __shfl_down(ssum, off, 32);
        if (lane==0) s_inv[qi] = 1.0f/ssum;
    }
    __syncthreads();
    {   // P @ V : 8 k-chunks x 32 dims
        int chunk = t >> 5, d = t & 31;
        float acc[QT] = {};
        for (int k=chunk; k<QQ; k+=8) {
            float v = qkv[((size_t)(b*QQ+k))*768 + 512 + h*HD + d];
            #pragma unroll
            for (int qi=0; qi<QT; qi++) acc[qi] += s_sc[qi][k]*v;
        }
        #pragma unroll
        for (int qi=0; qi<QT; qi++) s_o[chunk][qi][d] = acc[qi];
    }
    __syncthreads();
    {
        int qi = t >> 5, d = t & 31;
        int gq = q0 + qi;
        if (gq < QQ) {
            float acc = 0.f;
            #pragma unroll
            for (int ch=0; ch<8; ch++) acc += s_o[ch][qi][d];
            attn_out[((size_t)(b*QQ+gq))*DD + h*HD + d] = acc * s_inv[qi];
        }
    }
}

// ---------------- layernorm + cls/box heads ----------------
__global__ __launch_bounds__(256) void final_kernel(const float* __restrict__ o,
    const float* __restrict__ norm_w, const float* __restrict__ norm_b,
    const float* __restrict__ cls_w, const float* __restrict__ cls_b,
    const float* __restrict__ box_w, const float* __restrict__ box_b,
    float* __restrict__ out) {
    __shared__ float s_xn[DD];
    __shared__ float red[8];
    int bq = blockIdx.x;
    int t = threadIdx.x;
    float val = o[(size_t)bq*DD + t];
    float v1 = val, v2 = val*val;
    for (int off=32; off>0; off>>=1) { v1 += __shfl_down(v1, off); v2 += __shfl_down(v2, off); }
    if ((t & 63) == 0) { red[t>>6] = v1; red[4 + (t>>6)] = v2; }
    __syncthreads();
    float ssum = red[0]+red[1]+red[2]+red[3];
    float ssq  = red[4]+red[5]+red[6]+red[7];
    float mu = ssum / (float)DD;
    float var = ssq / (float)DD - mu*mu;
    float inv = 1.0f / sqrtf(var + 1e-5f);
    s_xn[t] = (val - mu)*inv*norm_w[t] + norm_b[t];
    __syncthreads();
    int j = t >> 5, lane = t & 31;
    const float* wrow = (j < 2) ? (cls_w + j*DD) : (box_w + (j-2)*DD);
    float acc = 0.f;
    for (int k=lane; k<DD; k+=32) acc += s_xn[k]*wrow[k];
    for (int off=16; off>0; off>>=1) acc += __shfl_down(acc, off, 32);
    if (lane == 0) {
        if (j < 2) {
            out[(size_t)bq*2 + j] = acc + cls_b[j];
        } else {
            int jj = j-2;
            float v = acc + box_b[jj];
            if (jj < 3) v = sigmoidf_(v);
            out[BB*QQ*2 + (size_t)bq*6 + jj] = v;
        }
    }
}

extern "C" void kernel_launch(void* const* d_in, const int* in_sizes, int n_in,
                              void* d_out, int out_size, void* d_ws, size_t ws_size,
                              hipStream_t stream) {
    const float* feats = (const float*)d_in[0];
    const float* l2i   = (const float*)d_in[1];
    const float* qe    = (const float*)d_in[2];
    const float* ref_w = (const float*)d_in[3];
    const float* ref_b = (const float*)d_in[4];
    const float* ipw   = (const float*)d_in[5];
    const float* ipb   = (const float*)d_in[6];
    const float* opw   = (const float*)d_in[7];
    const float* opb   = (const float*)d_in[8];
    const float* nw    = (const float*)d_in[9];
    const float* nb    = (const float*)d_in[10];
    const float* clsw  = (const float*)d_in[11];
    const float* clsb  = (const float*)d_in[12];
    const float* boxw  = (const float*)d_in[13];
    const float* boxb  = (const float*)d_in[14];
    float* out = (float*)d_out;
    float* ws = (float*)d_ws;

    float* ref   = ws;                         // 2700
    float* wxa   = ws + 2700;                  // 10800
    float* wya   = wxa + 10800;                // 10800
    int*   x0a   = (int*)(wya + 10800);        // 10800
    int*   y0a   = x0a + 10800;                // 10800
    int*   maskz = y0a + 10800;                // 10800
    int*   inimg = maskz + 10800;              // 10800
    float* x     = (float*)(inimg + 10800);    // 1800*256
    float* qkv   = x + 460800;                 // 1800*768
    float* attn  = qkv + 1382400;              // 1800*256
    float* oproj = attn + 460800;              // 1800*256

    ref_kernel<<<(QQ*3+255)/256, 256, 0, stream>>>(qe, ref_w, ref_b, ref);
    proj_kernel<<<(BB*NCAM*QQ+255)/256, 256, 0, stream>>>(l2i, ref, wxa, wya, x0a, y0a, maskz, inimg);
    sample_kernel<<<BB*QQ, 256, 0, stream>>>(feats, qe, wxa, wya, x0a, y0a, maskz, inimg, x);
    sgemm_nt<<<dim3(768/TILE, (BB*QQ+TILE-1)/TILE), 256, 0, stream>>>(x, ipw, ipb, qkv, BB*QQ, 768, 256);
    attn_kernel<<<BB*NHD*((QQ+QT-1)/QT), 256, 0, stream>>>(qkv, attn);
    sgemm_nt<<<dim3(256/TILE, (BB*QQ+TILE-1)/TILE), 256, 0, stream>>>(attn, opw, opb, oproj, BB*QQ, 256, 256);
    final_kernel<<<BB*QQ, 256, 0, stream>>>(oproj, nw, nb, clsw, clsb, boxw, boxb, out);
}

// Round 3
// 504.445 us; speedup vs baseline: 1.3860x; 1.3860x over previous
//
#include <hip/hip_runtime.h>
#include <math.h>

#define BB 2
#define NCAM 6
#define CC 256
#define HH 116
#define WW 200
#define QQ 900
#define DD 256
#define NHD 8
#define HD 32
#define HWSZ (HH*WW)

__device__ __forceinline__ float sigmoidf_(float x){ return 1.0f/(1.0f+expf(-x)); }

// ---------------- ref = sigmoid(q @ ref_w.T + ref_b)  [Q,3] ----------------
__global__ void ref_kernel(const float* __restrict__ qe, const float* __restrict__ ref_w,
                           const float* __restrict__ ref_b, float* __restrict__ ref) {
    int idx = blockIdx.x*256 + threadIdx.x;
    if (idx >= QQ*3) return;
    int q = idx/3, j = idx%3;
    float acc = ref_b[j];
    const float* qr = qe + q*DD;
    const float* wr = ref_w + j*DD;
    for (int k=0;k<DD;k++) acc += qr[k]*wr[k];
    ref[idx] = sigmoidf_(acc);
}

// ---------------- project ref points to each camera ----------------
__global__ void proj_kernel(const float* __restrict__ l2i, const float* __restrict__ ref,
        float* __restrict__ wxa, float* __restrict__ wya,
        int* __restrict__ x0a, int* __restrict__ y0a,
        int* __restrict__ maskz, int* __restrict__ inimg) {
    int idx = blockIdx.x*256+threadIdx.x;
    if (idx >= BB*NCAM*QQ) return;
    int q = idx % QQ;
    int bn = idx / QQ;   // b*NCAM+n
    float h0 = ref[q*3+0], h1 = ref[q*3+1], h2 = ref[q*3+2];
    const float* m = l2i + bn*16;
    float px = m[0]*h0+m[1]*h1+m[2]*h2+m[3];
    float py = m[4]*h0+m[5]*h1+m[6]*h2+m[7];
    float pz = m[8]*h0+m[9]*h1+m[10]*h2+m[11];
    float denom = fabsf(pz)+1e-5f;
    float sx = px/denom, sy = py/denom;
    float pnx = sx/(float)(WW-1)*2.0f-1.0f;
    float pny = sy/(float)(HH-1)*2.0f-1.0f;
    maskz[idx] = (pz > 1e-5f) ? 1 : 0;
    inimg[idx] = (fmaxf(fabsf(pnx),fabsf(pny)) < 1.0f) ? 1 : 0;
    float ix = (pnx+1.0f)*(WW*0.5f)-0.5f;
    float iy = (pny+1.0f)*(HH*0.5f)-0.5f;
    float x0f = floorf(ix), y0f = floorf(iy);
    wxa[idx] = ix-x0f; wya[idx] = iy-y0f;
    x0a[idx] = (int)x0f; y0a[idx] = (int)y0f;
}

// ---------------- bilinear gather + masked mean over cams + add q ----------------
__global__ __launch_bounds__(256) void sample_kernel(const float* __restrict__ feats,
        const float* __restrict__ qe, const float* __restrict__ wxa, const float* __restrict__ wya,
        const int* __restrict__ x0a, const int* __restrict__ y0a,
        const int* __restrict__ maskz, const int* __restrict__ inimg,
        float* __restrict__ xout) {
    int bq = blockIdx.x;
    int b = bq / QQ, q = bq % QQ;
    int c = threadIdx.x;
    float sum = 0.0f;
    int cnt = 0;
    for (int n = 0; n < NCAM; n++) {
        int s = (b*NCAM+n)*QQ + q;          // matched (b,n,q) index
        int sq = b*(NCAM*QQ) + q*NCAM + n;  // reference's reshape-scrambled index
        int v = maskz[s] & inimg[sq];
        if (!v) continue;
        cnt++;
        float wx = wxa[s], wy = wya[s];
        int x0 = x0a[s], y0 = y0a[s];
        int x1 = x0+1, y1 = y0+1;
        const float* fb = feats + ((size_t)(b*NCAM+n)*CC + c)*HWSZ;
        float w00 = (1.f-wx)*(1.f-wy), w10 = wx*(1.f-wy), w01 = (1.f-wx)*wy, w11 = wx*wy;
        bool xin0 = ((unsigned)x0 < (unsigned)WW);
        bool xin1 = ((unsigned)x1 < (unsigned)WW);
        if ((unsigned)y0 < (unsigned)HH) {
            const float* row = fb + y0*WW;
            if (xin0) sum += w00*row[x0];
            if (xin1) sum += w10*row[x1];
        }
        if ((unsigned)y1 < (unsigned)HH) {
            const float* row = fb + y1*WW;
            if (xin0) sum += w01*row[x0];
            if (xin1) sum += w11*row[x1];
        }
    }
    float tgt = sum / (float)(cnt > 0 ? cnt : 1);
    xout[(size_t)bq*DD + c] = qe[q*DD+c] + tgt;
}

// ---------------- tiled SGEMM: C[M,N] = A[M,K] @ Wt[N,K]^T + bias[N] ----------------
#define TILE 64
#define BKK 16
__global__ __launch_bounds__(256) void sgemm_nt(const float* __restrict__ A,
        const float* __restrict__ Bw, const float* __restrict__ bias,
        float* __restrict__ Cm, int M, int N, int K) {
    __shared__ float As[BKK][TILE];
    __shared__ float Bs[BKK][TILE];
    int tid = threadIdx.x;
    int m0 = blockIdx.y * TILE, n0 = blockIdx.x * TILE;
    float acc[4][4] = {};
    int tx = tid & 15, ty = tid >> 4;
    for (int k0 = 0; k0 < K; k0 += BKK) {
        #pragma unroll
        for (int i = 0; i < 4; i++) {
            int idx = tid + i * 256;
            int m = idx >> 4;
            int k = idx & 15;
            int gm = m0 + m;
            As[k][m] = (gm < M) ? A[(size_t)gm * K + k0 + k] : 0.0f;
            int gn = n0 + m;
            Bs[k][m] = (gn < N) ? Bw[(size_t)gn * K + k0 + k] : 0.0f;
        }
        __syncthreads();
        #pragma unroll
        for (int k = 0; k < BKK; k++) {
            float a[4], bb[4];
            #pragma unroll
            for (int i = 0; i < 4; i++) a[i] = As[k][ty*4+i];
            #pragma unroll
            for (int j = 0; j < 4; j++) bb[j] = Bs[k][tx*4+j];
            #pragma unroll
            for (int i = 0; i < 4; i++)
                #pragma unroll
                for (int j = 0; j < 4; j++)
                    acc[i][j] += a[i] * bb[j];
        }
        __syncthreads();
    }
    for (int i = 0; i < 4; i++) {
        int gm = m0 + ty*4 + i;
        if (gm >= M) continue;
        for (int j = 0; j < 4; j++) {
            int gn = n0 + tx*4 + j;
            if (gn < N) Cm[(size_t)gm * N + gn] = acc[i][j] + bias[gn];
        }
    }
}

// ---------------- flash-style attention: block per (b, h, 32-query tile) ----------------
// No max-subtraction: scores are O(1) here (softmax is shift-invariant; exp can't overflow).
#define QTILE 32
#define KTILE 64
#define NQB 29
__global__ __launch_bounds__(256) void attn_flash(const float* __restrict__ qkv,
                                                  float* __restrict__ attn_out) {
    __shared__ __align__(16) float Qs[32][36];   // [d][q]  bank-safe pad
    __shared__ __align__(16) float Ks[32][68];   // [d][k]  rows 16B-aligned (272B)
    __shared__ __align__(16) float Vs[64][36];   // [k][d]
    __shared__ __align__(16) float Ps[32][68];   // [q][k]
    int blk = blockIdx.x;
    int qb = blk % NQB;
    int h  = (blk / NQB) % NHD;
    int b  = blk / (NQB*NHD);
    int q0 = qb * QTILE;
    int tid = threadIdx.x;
    int tx = tid & 15, ty = tid >> 4;

    // load Q tile transposed: Qs[d][q]
    {
        int q = tid >> 3;            // 0..31
        int dseg = (tid & 7) * 4;
        int gq = q0 + q; if (gq > QQ-1) gq = QQ-1;
        const float4 f = *(const float4*)(qkv + ((size_t)(b*QQ+gq))*768 + h*HD + dseg);
        Qs[dseg+0][q] = f.x; Qs[dseg+1][q] = f.y; Qs[dseg+2][q] = f.z; Qs[dseg+3][q] = f.w;
    }

    float O[2][2] = {};
    float l[2] = {0.f, 0.f};
    const float scale = 0.17677669529663689f; // 1/sqrt(32)

    for (int k0 = 0; k0 < QQ; k0 += KTILE) {
        // stage K (transposed) and V tiles
        {
            int k = tid >> 2;            // 0..63
            int dseg = (tid & 3) * 8;
            int gk = k0 + k; if (gk > QQ-1) gk = QQ-1;
            const float* kp = qkv + ((size_t)(b*QQ+gk))*768 + 256 + h*HD + dseg;
            float4 f0 = *(const float4*)(kp);
            float4 f1 = *(const float4*)(kp+4);
            Ks[dseg+0][k]=f0.x; Ks[dseg+1][k]=f0.y; Ks[dseg+2][k]=f0.z; Ks[dseg+3][k]=f0.w;
            Ks[dseg+4][k]=f1.x; Ks[dseg+5][k]=f1.y; Ks[dseg+6][k]=f1.z; Ks[dseg+7][k]=f1.w;
            const float* vp = qkv + ((size_t)(b*QQ+gk))*768 + 512 + h*HD + dseg;
            *(float4*)(&Vs[k][dseg])   = *(const float4*)(vp);
            *(float4*)(&Vs[k][dseg+4]) = *(const float4*)(vp+4);
        }
        __syncthreads();

        // scores: 2q x 4k register fragment
        float acc[2][4] = {};
        #pragma unroll
        for (int d = 0; d < 32; d++) {
            float a0 = Qs[d][ty*2];
            float a1 = Qs[d][ty*2+1];
            float4 bk = *(const float4*)(&Ks[d][tx*4]);
            acc[0][0] += a0*bk.x; acc[0][1] += a0*bk.y; acc[0][2] += a0*bk.z; acc[0][3] += a0*bk.w;
            acc[1][0] += a1*bk.x; acc[1][1] += a1*bk.y; acc[1][2] += a1*bk.z; acc[1][3] += a1*bk.w;
        }
        // exp + tail mask + row-sum across tx
        #pragma unroll
        for (int i = 0; i < 2; i++) {
            float e[4];
            float rs = 0.f;
            #pragma unroll
            for (int j = 0; j < 4; j++) {
                int gk = k0 + tx*4 + j;
                float v = (gk < QQ) ? expf(acc[i][j]*scale) : 0.f;
                e[j] = v; rs += v;
            }
            #pragma unroll
            for (int m = 1; m < 16; m <<= 1) rs += __shfl_xor(rs, m, 16);
            l[i] += rs;
            *(float4*)(&Ps[ty*2+i][tx*4]) = make_float4(e[0],e[1],e[2],e[3]);
        }
        __syncthreads();

        // PV: O[2q][2d] accumulate
        #pragma unroll
        for (int k4 = 0; k4 < 16; k4++) {
            float4 p0 = *(const float4*)(&Ps[ty*2][k4*4]);
            float4 p1 = *(const float4*)(&Ps[ty*2+1][k4*4]);
            float2 v0 = *(const float2*)(&Vs[k4*4+0][tx*2]);
            float2 v1 = *(const float2*)(&Vs[k4*4+1][tx*2]);
            float2 v2 = *(const float2*)(&Vs[k4*4+2][tx*2]);
            float2 v3 = *(const float2*)(&Vs[k4*4+3][tx*2]);
            O[0][0] += p0.x*v0.x + p0.y*v1.x + p0.z*v2.x + p0.w*v3.x;
            O[0][1] += p0.x*v0.y + p0.y*v1.y + p0.z*v2.y + p0.w*v3.y;
            O[1][0] += p1.x*v0.x + p1.y*v1.x + p1.z*v2.x + p1.w*v3.x;
            O[1][1] += p1.x*v0.y + p1.y*v1.y + p1.z*v2.y + p1.w*v3.y;
        }
        __syncthreads();
    }

    #pragma unroll
    for (int i = 0; i < 2; i++) {
        int gq = q0 + ty*2 + i;
        if (gq < QQ) {
            float inv = 1.0f / l[i];
            float* op = attn_out + ((size_t)(b*QQ+gq))*DD + h*HD + tx*2;
            op[0] = O[i][0]*inv;
            op[1] = O[i][1]*inv;
        }
    }
}

// ---------------- layernorm + cls/box heads ----------------
__global__ __launch_bounds__(256) void final_kernel(const float* __restrict__ o,
    const float* __restrict__ norm_w, const float* __restrict__ norm_b,
    const float* __restrict__ cls_w, const float* __restrict__ cls_b,
    const float* __restrict__ box_w, const float* __restrict__ box_b,
    float* __restrict__ out) {
    __shared__ float s_xn[DD];
    __shared__ float red[8];
    int bq = blockIdx.x;
    int t = threadIdx.x;
    float val = o[(size_t)bq*DD + t];
    float v1 = val, v2 = val*val;
    for (int off=32; off>0; off>>=1) { v1 += __shfl_down(v1, off); v2 += __shfl_down(v2, off); }
    if ((t & 63) == 0) { red[t>>6] = v1; red[4 + (t>>6)] = v2; }
    __syncthreads();
    float ssum = red[0]+red[1]+red[2]+red[3];
    float ssq  = red[4]+red[5]+red[6]+red[7];
    float mu = ssum / (float)DD;
    float var = ssq / (float)DD - mu*mu;
    float inv = 1.0f / sqrtf(var + 1e-5f);
    s_xn[t] = (val - mu)*inv*norm_w[t] + norm_b[t];
    __syncthreads();
    int j = t >> 5, lane = t & 31;
    const float* wrow = (j < 2) ? (cls_w + j*DD) : (box_w + (j-2)*DD);
    float acc = 0.f;
    for (int k=lane; k<DD; k+=32) acc += s_xn[k]*wrow[k];
    for (int off=16; off>0; off>>=1) acc += __shfl_down(acc, off, 32);
    if (lane == 0) {
        if (j < 2) {
            out[(size_t)bq*2 + j] = acc + cls_b[j];
        } else {
            int jj = j-2;
            float v = acc + box_b[jj];
            if (jj < 3) v = sigmoidf_(v);
            out[BB*QQ*2 + (size_t)bq*6 + jj] = v;
        }
    }
}

extern "C" void kernel_launch(void* const* d_in, const int* in_sizes, int n_in,
                              void* d_out, int out_size, void* d_ws, size_t ws_size,
                              hipStream_t stream) {
    const float* feats = (const float*)d_in[0];
    const float* l2i   = (const float*)d_in[1];
    const float* qe    = (const float*)d_in[2];
    const float* ref_w = (const float*)d_in[3];
    const float* ref_b = (const float*)d_in[4];
    const float* ipw   = (const float*)d_in[5];
    const float* ipb   = (const float*)d_in[6];
    const float* opw   = (const float*)d_in[7];
    const float* opb   = (const float*)d_in[8];
    const float* nw    = (const float*)d_in[9];
    const float* nb    = (const float*)d_in[10];
    const float* clsw  = (const float*)d_in[11];
    const float* clsb  = (const float*)d_in[12];
    const float* boxw  = (const float*)d_in[13];
    const float* boxb  = (const float*)d_in[14];
    float* out = (float*)d_out;
    float* ws = (float*)d_ws;

    float* ref   = ws;                         // 2700
    float* wxa   = ws + 2700;                  // 10800
    float* wya   = wxa + 10800;                // 10800
    int*   x0a   = (int*)(wya + 10800);        // 10800
    int*   y0a   = x0a + 10800;                // 10800
    int*   maskz = y0a + 10800;                // 10800
    int*   inimg = maskz + 10800;              // 10800
    float* x     = (float*)(inimg + 10800);    // 1800*256
    float* qkv   = x + 460800;                 // 1800*768
    float* attn  = qkv + 1382400;              // 1800*256
    float* oproj = attn + 460800;              // 1800*256

    ref_kernel<<<(QQ*3+255)/256, 256, 0, stream>>>(qe, ref_w, ref_b, ref);
    proj_kernel<<<(BB*NCAM*QQ+255)/256, 256, 0, stream>>>(l2i, ref, wxa, wya, x0a, y0a, maskz, inimg);
    sample_kernel<<<BB*QQ, 256, 0, stream>>>(feats, qe, wxa, wya, x0a, y0a, maskz, inimg, x);
    sgemm_nt<<<dim3(768/TILE, (BB*QQ+TILE-1)/TILE), 256, 0, stream>>>(x, ipw, ipb, qkv, BB*QQ, 768, 256);
    attn_flash<<<BB*NHD*NQB, 256, 0, stream>>>(qkv, attn);
    sgemm_nt<<<dim3(256/TILE, (BB*QQ+TILE-1)/TILE), 256, 0, stream>>>(attn, opw, opb, oproj, BB*QQ, 256, 256);
    final_kernel<<<BB*QQ, 256, 0, stream>>>(oproj, nw, nb, clsw, clsb, boxw, boxb, out);
}